// Round 9
// baseline (177.069 us; speedup 1.0000x reference)
//
#include <hip/hip_runtime.h>
#include <math.h>

// Problem constants (fixed by the reference)
#define NQ   1024      // B*LT
#define DIM  512
#define NH   8
#define DHD  64
#define DFF  2048
#define LM   64        // LMEM
#define NMEM 1024

typedef __bf16 bf16x8 __attribute__((ext_vector_type(8)));
typedef float  f32x4  __attribute__((ext_vector_type(4)));

__device__ __forceinline__ unsigned short f2bf(float f) {
    unsigned u = __builtin_bit_cast(unsigned, f);
    return (unsigned short)((u + 0x7fffu + ((u >> 16) & 1u)) >> 16);
}
__device__ __forceinline__ float bflo(unsigned p) {
    return __builtin_bit_cast(float, p << 16);
}
__device__ __forceinline__ float bfhi(unsigned p) {
    return __builtin_bit_cast(float, p & 0xffff0000u);
}

__device__ __forceinline__ void gload16(const void* g, void* l) {
    __builtin_amdgcn_global_load_lds(
        (const __attribute__((address_space(1))) unsigned*)g,
        (__attribute__((address_space(3))) unsigned*)l, 16, 0, 0);
}

// ---------------------------------------------------------------- helpers
__device__ __forceinline__ float blk_sum(float v, volatile float* red) {
#pragma unroll
    for (int o = 32; o; o >>= 1) v += __shfl_down(v, o);
    __syncthreads();
    if ((threadIdx.x & 63) == 0) red[threadIdx.x >> 6] = v;
    __syncthreads();
    return red[0] + red[1] + red[2] + red[3];
}

// ------------------------------------------------- K1: weight-prep + LN0 + argmax
struct PrepPtrs {
    const float* src[8];
    unsigned short* dst[8];
};
// blocks [0,5120): weight prep; blocks [5120,6144): LN0+argmax for n = bid-5120
__global__ __launch_bounds__(256) void prep_ln0_k(
    PrepPtrs p,
    const float* __restrict__ dec_out, const float* __restrict__ attn_out,
    const float* __restrict__ g, const float* __restrict__ be,
    float* __restrict__ x, unsigned* __restrict__ xb, int* __restrict__ samples)
{
    __shared__ float tile[32][33];
    __shared__ float red[4];
    __shared__ float rv[4]; __shared__ int ri[4];
    const int bid = blockIdx.x;

    if (bid < 5120) {
        int m, lt;
        if (bid < 1024) { m = bid >> 8; lt = bid & 255; }
        else { m = 4 + ((bid - 1024) >> 10); lt = (bid - 1024) & 1023; }
        const int RS = (m < 4) ? 512 : ((m == 5 || m == 7) ? 2048 : 512);
        const int CS = (m < 4) ? 512 : ((m == 5 || m == 7) ? 512 : 2048);
        const int TC = CS >> 5;
        const int tr = lt / TC, tc = lt % TC;
        const float* s = p.src[m];
        unsigned short* d = p.dst[m];
        const int tx = threadIdx.x & 31, ty = threadIdx.x >> 5;
        if (m == 1) {
#pragma unroll
            for (int i = 0; i < 32; i += 8) {
                size_t idx = (size_t)(tr * 32 + ty + i) * CS + tc * 32 + tx;
                d[idx] = f2bf(s[idx]);
            }
        } else {
#pragma unroll
            for (int i = 0; i < 32; i += 8)
                tile[ty + i][tx] = s[(size_t)(tr * 32 + ty + i) * CS + tc * 32 + tx];
            __syncthreads();
#pragma unroll
            for (int i = 0; i < 32; i += 8)
                d[(size_t)(tc * 32 + ty + i) * RS + tr * 32 + tx] = f2bf(tile[tx][ty + i]);
        }
        return;
    }

    const int n = bid - 5120, t = threadIdx.x;
    float2 v = ((const float2*)(dec_out + (size_t)n * DIM))[t];
    float mu  = blk_sum(v.x + v.y, red) * (1.f / DIM);
    float dx = v.x - mu, dy = v.y - mu;
    float var = blk_sum(dx * dx + dy * dy, red) * (1.f / DIM);
    float rs = rsqrtf(var + 1e-5f);
    float2 gg = ((const float2*)g)[t], bb = ((const float2*)be)[t];
    float ox = dx * rs * gg.x + bb.x, oy = dy * rs * gg.y + bb.y;
    ((float2*)(x + (size_t)n * DIM))[t] = make_float2(ox, oy);
    xb[(size_t)n * 256 + t] = (unsigned)f2bf(ox) | ((unsigned)f2bf(oy) << 16);

    const float* ar = attn_out + (size_t)n * 1025;
    float bv = -INFINITY; int bi = 0x7fffffff;
    for (int i = t; i < 1025; i += 256) {
        float val = ar[i];
        if (val > bv || (val == bv && i < bi)) { bv = val; bi = i; }
    }
#pragma unroll
    for (int o = 32; o; o >>= 1) {
        float ov = __shfl_down(bv, o); int oi = __shfl_down(bi, o);
        if (ov > bv || (ov == bv && oi < bi)) { bv = ov; bi = oi; }
    }
    if ((t & 63) == 0) { rv[t >> 6] = bv; ri[t >> 6] = bi; }
    __syncthreads();
    if (t == 0) {
#pragma unroll
        for (int w = 1; w < 4; ++w)
            if (rv[w] > bv || (rv[w] == bv && ri[w] < bi)) { bv = rv[w]; bi = ri[w]; }
        samples[n] = bi - 1;
    }
}

// ------------------------------------------------- K2: build per-memory query groups
__global__ __launch_bounds__(1024) void group_build_k(
    const int* __restrict__ samples, int* __restrict__ qcount,
    int* __restrict__ qstart, int* __restrict__ qlist)
{
    __shared__ int cnt[NMEM];
    __shared__ int base[NMEM];
    __shared__ int wsum[16];
    const int t = threadIdx.x;
    cnt[t] = 0;
    __syncthreads();
    int s = samples[t]; if (s < 0) s = 0;
    atomicAdd(&cnt[s], 1);
    __syncthreads();
    const int c = cnt[t];
    int v = c;
    const int lane = t & 63, w = t >> 6;
#pragma unroll
    for (int o = 1; o < 64; o <<= 1) {
        int u = __shfl_up(v, o);
        if (lane >= o) v += u;
    }
    if (lane == 63) wsum[w] = v;
    __syncthreads();
    if (w == 0) {
        int x = (lane < 16) ? wsum[lane] : 0;
#pragma unroll
        for (int o = 1; o < 16; o <<= 1) {
            int u = __shfl_up(x, o);
            if (lane >= o) x += u;
        }
        if (lane < 16) wsum[lane] = x;
    }
    __syncthreads();
    const int start = v - c + (w ? wsum[w - 1] : 0);
    base[t] = start;
    qstart[t] = start;
    qcount[t] = c;
    __syncthreads();
    cnt[t] = 0;
    __syncthreads();
    int pos = atomicAdd(&cnt[s], 1);
    qlist[base[s] + pos] = t;
}

// ------------------------------------------------- bf16 MFMA GEMM, 64x64 tile
// XCD-aware tile swizzle: requires gridDim.x*gridDim.y % 8 == 0.
template<bool RELU, bool BIAS, bool RES, bool WF32, bool WBF>
__global__ __launch_bounds__(256) void mfma_gemm(
    const unsigned short* __restrict__ A, const unsigned short* __restrict__ Bt,
    float* __restrict__ Cf, unsigned short* __restrict__ Cb,
    const float* __restrict__ bias, const float* __restrict__ res,
    int K, int lda, int ldb, int ldc,
    int sA, int sB, int sC, int sBias)
{
    __shared__ unsigned short Ab[2][64 * 64];
    __shared__ unsigned short Bb[2][64 * 64];
    const int t = threadIdx.x, lane = t & 63, wid = t >> 6;
    const int nx = gridDim.x;
    const int fid = blockIdx.y * nx + blockIdx.x;
    const int cpx = (nx * gridDim.y) >> 3;
    const int f2 = (fid & 7) * cpx + (fid >> 3);
    const int bn = (f2 % nx) * 64, bm = (f2 / nx) * 64, bz = blockIdx.z;
    const unsigned short* Abase = A + (size_t)bz * sA + (size_t)bm * lda;
    const unsigned short* Bbase = Bt + (size_t)bz * sB + (size_t)bn * ldb;

    const int r0 = wid * 16 + (lane >> 3);
    const int cbs = lane & 7;

#define STAGE_T(buf, base, ld, kt)                                              \
    {                                                                           \
        int r_ = r0;                                                            \
        gload16(base + (size_t)r_ * ld + (kt) * 64 + ((cbs ^ (r_ & 7)) << 3),   \
                &buf[(wid * 2 + 0) * 512]);                                     \
        r_ = r0 + 8;                                                            \
        gload16(base + (size_t)r_ * ld + (kt) * 64 + ((cbs ^ (r_ & 7)) << 3),   \
                &buf[(wid * 2 + 1) * 512]);                                     \
    }

    const int lr = lane & 15, lg = lane >> 4;
    const int wr = (wid >> 1) * 32, wc = (wid & 1) * 32;
    const int mA0 = wr + lr, mA1 = wr + 16 + lr;
    const int nB0 = wc + lr, nB1 = wc + 16 + lr;
    f32x4 acc[2][2] = {};

#define COMPUTE(b)                                                              \
    _Pragma("unroll")                                                           \
    for (int kk = 0; kk < 2; ++kk) {                                            \
        const int kb = kk * 4 + lg;                                             \
        bf16x8 a0 = *(const bf16x8*)&Ab[b][mA0 * 64 + ((kb ^ (mA0 & 7)) << 3)]; \
        bf16x8 a1 = *(const bf16x8*)&Ab[b][mA1 * 64 + ((kb ^ (mA1 & 7)) << 3)]; \
        bf16x8 b0 = *(const bf16x8*)&Bb[b][nB0 * 64 + ((kb ^ (nB0 & 7)) << 3)]; \
        bf16x8 b1 = *(const bf16x8*)&Bb[b][nB1 * 64 + ((kb ^ (nB1 & 7)) << 3)]; \
        acc[0][0] = __builtin_amdgcn_mfma_f32_16x16x32_bf16(a0, b0, acc[0][0], 0, 0, 0); \
        acc[0][1] = __builtin_amdgcn_mfma_f32_16x16x32_bf16(a0, b1, acc[0][1], 0, 0, 0); \
        acc[1][0] = __builtin_amdgcn_mfma_f32_16x16x32_bf16(a1, b0, acc[1][0], 0, 0, 0); \
        acc[1][1] = __builtin_amdgcn_mfma_f32_16x16x32_bf16(a1, b1, acc[1][1], 0, 0, 0); \
    }

    STAGE_T(Ab[0], Abase, lda, 0);
    STAGE_T(Bb[0], Bbase, ldb, 0);
    __syncthreads();
    const int NT = K >> 6;
    int cur = 0;
    for (int kt = 0; kt < NT; ++kt) {
        if (kt + 1 < NT) {
            STAGE_T(Ab[cur ^ 1], Abase, lda, kt + 1);
            STAGE_T(Bb[cur ^ 1], Bbase, ldb, kt + 1);
        }
        if (cur == 0) { COMPUTE(0); } else { COMPUTE(1); }
        __syncthreads();
        cur ^= 1;
    }

#pragma unroll
    for (int fm = 0; fm < 2; ++fm)
#pragma unroll
    for (int fn = 0; fn < 2; ++fn) {
        const int col = bn + wc + fn * 16 + lr;
        float bia = BIAS ? bias[bz * sBias + col] : 0.f;
#pragma unroll
        for (int r = 0; r < 4; ++r) {
            const int row = bm + wr + fm * 16 + lg * 4 + r;
            const size_t ci = (size_t)bz * sC + (size_t)row * ldc + col;
            float v = acc[fm][fn][r] + bia;
            if (RES) v += res[(size_t)row * ldc + col];
            if (RELU) v = fmaxf(v, 0.f);
            if (WF32) Cf[ci] = v;
            if (WBF)  Cb[ci] = f2bf(v);
        }
    }
#undef STAGE_T
#undef COMPUTE
}

// ------------------------------------------------- K5: grouped key-split scores
// block (s, kq): enc keys [kq*32,+32) loaded ONCE to bf16 registers, then loop
// over this memory's queries; per query emit P~=exp bf16 + (m,sum) stats.
__global__ __launch_bounds__(256) void attn_scores_k(
    const unsigned short* __restrict__ u_bf, const float* __restrict__ enc,
    const int* __restrict__ maskmem,
    const int* __restrict__ qcount, const int* __restrict__ qstart,
    const int* __restrict__ qlist,
    unsigned short* __restrict__ p_half, float* __restrict__ msc)
{
    __shared__ float S_lds[2][32][8];   // [dim-half][key][head]
    __shared__ int Msk_lds[32];
    const int s = blockIdx.x, kq = blockIdx.y, t = threadIdx.x;
    const int cnt = qcount[s];
    if (cnt == 0) return;
    const int lane = t & 63, w = t >> 6;

    // A-frags: wave w -> keys (w&1)*16..+16, dim-half (w>>1); load + cvt once
    const int keyloc = (w & 1) * 16 + (lane & 15);
    const int key = kq * 32 + keyloc;
    const int dh = w >> 1;
    const int lg = lane >> 4;
    const int h = lane & 15;
    const float4* kb = (const float4*)(enc + (size_t)s * (LM * DIM));
    const int base = key * 128 + dh * 64 + lg * 2;   // float4 units
    bf16x8 afr[8];
    {
        float4 buf[8][2];
#pragma unroll
        for (int st = 0; st < 8; ++st) {
            buf[st][0] = kb[base + st * 8];
            buf[st][1] = kb[base + st * 8 + 1];
        }
#pragma unroll
        for (int st = 0; st < 8; ++st) {
            float4 a0 = buf[st][0], a1 = buf[st][1];
            afr[st][0] = (__bf16)a0.x; afr[st][1] = (__bf16)a0.y;
            afr[st][2] = (__bf16)a0.z; afr[st][3] = (__bf16)a0.w;
            afr[st][4] = (__bf16)a1.x; afr[st][5] = (__bf16)a1.y;
            afr[st][6] = (__bf16)a1.z; afr[st][7] = (__bf16)a1.w;
        }
    }
    if (t < 32) Msk_lds[t] = maskmem[(size_t)s * LM + kq * 32 + t];

    const int qs = qstart[s];
    for (int g = 0; g < cnt; ++g) {
        const int q = qlist[qs + g];
        const unsigned short* ub =
            u_bf + (size_t)q * 4096 + (size_t)(h & 7) * 512 + dh * 256;
        f32x4 acc = {};
#pragma unroll
        for (int st = 0; st < 8; ++st) {
            bf16x8 bfr = *(const bf16x8*)&ub[(st * 4 + lg) * 8];
            acc = __builtin_amdgcn_mfma_f32_16x16x32_bf16(afr[st], bfr, acc, 0, 0, 0);
        }
        __syncthreads();   // prev iteration's softmax reads done
        if (h < 8) {
#pragma unroll
            for (int r = 0; r < 4; ++r)
                S_lds[dh][(w & 1) * 16 + lg * 4 + r][h] = acc[r];
        }
        __syncthreads();
        // partial softmax: thread t -> head t>>5, key t&31
        const int h2 = t >> 5, k2 = t & 31;
        float sc = (S_lds[0][k2][h2] + S_lds[1][k2][h2]) * 0.125f;
        sc = (Msk_lds[k2] != 0) ? sc : -1e9f;
        float m = sc;
#pragma unroll
        for (int o = 16; o; o >>= 1) m = fmaxf(m, __shfl_xor(m, o));
        float e = __expf(sc - m);
        float su = e;
#pragma unroll
        for (int o = 16; o; o >>= 1) su += __shfl_xor(su, o);
        p_half[((size_t)q * 2 + kq) * 256 + k2 * 8 + h2] = f2bf(e);
        if (k2 == 0)
            ((float2*)(msc + ((size_t)q * 2 + kq) * 16))[h2] = make_float2(m, su);
    }
}

// ------------------------------------------------- K6: grouped online-merge + PV
// block (s, dq): V quarter held in registers, loop over this memory's queries.
__global__ __launch_bounds__(256) void attn_pv_k(
    const unsigned short* __restrict__ p_half, const float* __restrict__ msc,
    const float* __restrict__ vemb,
    const int* __restrict__ qcount, const int* __restrict__ qstart,
    const int* __restrict__ qlist, unsigned* __restrict__ a_bf)
{
    __shared__ uint4 P_lds[64];       // [k][8 heads] bf16
    __shared__ float2 Red[3][8][64];
    __shared__ float Wh[2][8];
    const int s = blockIdx.x, dq = blockIdx.y, t = threadIdx.x;
    const int cnt = qcount[s];
    if (cnt == 0) return;

    // V quarter into registers: thread (c=t&63 dim-pair, kh=t>>6 key-group)
    const int c = t & 63, kh = t >> 6;
    const float2* vb = (const float2*)(vemb + (size_t)s * (LM * DIM)) + dq * 64 + c;
    float2 vreg[16];
#pragma unroll
    for (int i = 0; i < 16; ++i) vreg[i] = vb[(size_t)(kh * 16 + i) * 256];

    const int qs = qstart[s];
    for (int g = 0; g < cnt; ++g) {
        const int q = qlist[qs + g];
        __syncthreads();   // prev iteration's P/Red/Wh reads done
        if (t < 8) {
            float2 ms0 = ((const float2*)(msc + (size_t)q * 32))[t];
            float2 ms1 = ((const float2*)(msc + (size_t)q * 32 + 16))[t];
            float m = fmaxf(ms0.x, ms1.x);
            float w0 = __expf(ms0.x - m), w1 = __expf(ms1.x - m);
            float inv = 1.f / (ms0.y * w0 + ms1.y * w1);
            Wh[0][t] = w0 * inv; Wh[1][t] = w1 * inv;
        }
        __syncthreads();
        {   // normalized P tile: thread t -> key t>>2, head-pair t&3
            const int k = t >> 2, hp = t & 3, kq2 = k >> 5;
            unsigned v = ((const unsigned*)p_half)[((size_t)q * 2 + kq2) * 128 + (k & 31) * 4 + hp];
            float a = bflo(v) * Wh[kq2][hp * 2];
            float b = bfhi(v) * Wh[kq2][hp * 2 + 1];
            ((unsigned*)P_lds)[k * 4 + hp] = (unsigned)f2bf(a) | ((unsigned)f2bf(b) << 16);
        }
        __syncthreads();

        float2 acc8[8];
#pragma unroll
        for (int hh = 0; hh < 8; ++hh) acc8[hh] = make_float2(0.f, 0.f);
#pragma unroll
        for (int i = 0; i < 16; ++i) {
            const int k = kh * 16 + i;
            float2 v = vreg[i];
            uint4 pr = P_lds[k];
            float p0 = bflo(pr.x), p1 = bfhi(pr.x);
            float p2 = bflo(pr.y), p3 = bfhi(pr.y);
            float p4 = bflo(pr.z), p5 = bfhi(pr.z);
            float p6 = bflo(pr.w), p7 = bfhi(pr.w);
            acc8[0].x = fmaf(p0, v.x, acc8[0].x); acc8[0].y = fmaf(p0, v.y, acc8[0].y);
            acc8[1].x = fmaf(p1, v.x, acc8[1].x); acc8[1].y = fmaf(p1, v.y, acc8[1].y);
            acc8[2].x = fmaf(p2, v.x, acc8[2].x); acc8[2].y = fmaf(p2, v.y, acc8[2].y);
            acc8[3].x = fmaf(p3, v.x, acc8[3].x); acc8[3].y = fmaf(p3, v.y, acc8[3].y);
            acc8[4].x = fmaf(p4, v.x, acc8[4].x); acc8[4].y = fmaf(p4, v.y, acc8[4].y);
            acc8[5].x = fmaf(p5, v.x, acc8[5].x); acc8[5].y = fmaf(p5, v.y, acc8[5].y);
            acc8[6].x = fmaf(p6, v.x, acc8[6].x); acc8[6].y = fmaf(p6, v.y, acc8[6].y);
            acc8[7].x = fmaf(p7, v.x, acc8[7].x); acc8[7].y = fmaf(p7, v.y, acc8[7].y);
        }
        if (kh > 0) {
#pragma unroll
            for (int hh = 0; hh < 8; ++hh) Red[kh - 1][hh][c] = acc8[hh];
        }
        __syncthreads();
        if (kh == 0) {
            unsigned* an = a_bf + (size_t)q * 2048 + dq * 64;
#pragma unroll
            for (int hh = 0; hh < 8; ++hh) {
                float2 r0 = Red[0][hh][c], r1 = Red[1][hh][c], r2 = Red[2][hh][c];
                float ox = acc8[hh].x + r0.x + r1.x + r2.x;
                float oy = acc8[hh].y + r0.y + r1.y + r2.y;
                an[hh * 256 + c] = (unsigned)f2bf(ox) | ((unsigned)f2bf(oy) << 16);
            }
        }
    }
}

// ------------------------------------------------- K11: combine T1 parts + LN + mask + x
__global__ __launch_bounds__(256) void ln1_mask_add_k(
    const float* __restrict__ t1p, const float* __restrict__ st0,
    const float* __restrict__ b2, const float* __restrict__ g,
    const float* __restrict__ be, const int* __restrict__ samples,
    const float* __restrict__ x, float* __restrict__ dec, unsigned* __restrict__ decb)
{
    __shared__ float red[4];
    const int n = blockIdx.x, t = threadIdx.x;
    const size_t off = (size_t)n * DIM + t * 2;
    float2 p0 = *(const float2*)&t1p[off];
    float2 p1 = *(const float2*)&t1p[(size_t)NQ * DIM + off];
    float2 s0 = *(const float2*)&st0[off];
    float2 b2v = ((const float2*)b2)[t];
    float2 v = make_float2(p0.x + p1.x + s0.x + b2v.x, p0.y + p1.y + s0.y + b2v.y);
    float mu  = blk_sum(v.x + v.y, red) * (1.f / DIM);
    float dx = v.x - mu, dy = v.y - mu;
    float var = blk_sum(dx * dx + dy * dy, red) * (1.f / DIM);
    float rs = rsqrtf(var + 1e-5f);
    float2 gg = ((const float2*)g)[t], bb = ((const float2*)be)[t];
    float sx = dx * rs * gg.x + bb.x, sy = dy * rs * gg.y + bb.y;
    if (samples[n] < 0) { sx = 0.f; sy = 0.f; }
    float2 xx = *(const float2*)&x[off];
    float ox = xx.x + sx, oy = xx.y + sy;
    *(float2*)&dec[off] = make_float2(ox, oy);
    decb[(size_t)n * 256 + t] = (unsigned)f2bf(ox) | ((unsigned)f2bf(oy) << 16);
}

// ---------------------------------------------------------------- launcher
extern "C" void kernel_launch(void* const* d_in, const int* in_sizes, int n_in,
                              void* d_out, int out_size, void* d_ws, size_t ws_size,
                              hipStream_t stream)
{
    const float* dec_output = (const float*)d_in[0];
    const float* mem_attn   = (const float*)d_in[1];
    const float* enc_mem    = (const float*)d_in[2];
    const float* temb_mem   = (const float*)d_in[3];
    const int*   mask_mem   = (const int*)d_in[4];
    const float* g0  = (const float*)d_in[6];
    const float* be0 = (const float*)d_in[7];
    const float* g1  = (const float*)d_in[8];
    const float* be1 = (const float*)d_in[9];
    const float* Wq  = (const float*)d_in[10];
    const float* bq  = (const float*)d_in[11];
    const float* Wk  = (const float*)d_in[12];
    const float* Wv  = (const float*)d_in[14];
    const float* bv  = (const float*)d_in[15];
    const float* Wo  = (const float*)d_in[16];
    const float* bo  = (const float*)d_in[17];
    const float* f1W1 = (const float*)d_in[18];
    const float* f1b1 = (const float*)d_in[19];
    const float* f1W2 = (const float*)d_in[20];
    const float* f1b2 = (const float*)d_in[21];
    const float* f2W1 = (const float*)d_in[22];
    const float* f2b1 = (const float*)d_in[23];
    const float* f2W2 = (const float*)d_in[24];
    const float* f2b2 = (const float*)d_in[25];
    float* out = (float*)d_out;

    float* ws = (float*)d_ws;
    // persistent (offsets in floats)
    float*          x_f   = ws + 0;                          // 524288
    unsigned*       x_b   = (unsigned*)(ws + 524288);        // 262144
    unsigned short* qh_b  = (unsigned short*)(ws + 786432);  // 262144
    unsigned short* u_b   = (unsigned short*)(ws + 1048576); // 2097152
    unsigned short* a_b   = (unsigned short*)(ws + 3145728); // 2097152
    unsigned short* p_hlf = (unsigned short*)(ws + 5242880); // 262144 f (1 MB bf16)
    float*          msc   = ws + 5505024;                    // 32768 f
    unsigned short* wqt   = (unsigned short*)(ws + 7340032); // 131072 each
    unsigned short* wkc   = (unsigned short*)(ws + 7471104);
    unsigned short* wvt   = (unsigned short*)(ws + 7602176);
    unsigned short* wot   = (unsigned short*)(ws + 7733248);
    unsigned short* f1w1t = (unsigned short*)(ws + 7864320); // 524288 each
    unsigned short* f1w2t = (unsigned short*)(ws + 8388608);
    unsigned short* f2w1t = (unsigned short*)(ws + 8912896);
    unsigned short* f2w2t = (unsigned short*)(ws + 9437184);
    int*            smp   = (int*)(ws + 9961472);            // 1024
    int*            qcnt  = (int*)(ws + 9962496);            // 1024
    int*            qsta  = (int*)(ws + 9963520);            // 1024
    int*            qlst  = (int*)(ws + 9964544);            // 1024
    float*          t1p_f = ws + 9965568;                    // 1048576 (2 parts)
    // aliases inside u_b region (u dead after attn_scores):
    float*          st0_f = (float*)u_b + 0;                 // 524288
    unsigned short* st0_b = (unsigned short*)((float*)u_b + 524288); // 131072
    float*          dec_f = (float*)u_b + 655360;            // 524288
    unsigned*       dec_b = (unsigned*)((float*)u_b + 1179648); // 131072
    // aliases inside a_b region (a dead after CTX GEMM):
    unsigned short* h1_b  = a_b;                             // 1024x2048 bf16
    unsigned short* h2_b  = (unsigned short*)((float*)a_b + 1048576);

    PrepPtrs pp;
    pp.src[0] = Wq;   pp.dst[0] = wqt;
    pp.src[1] = Wk;   pp.dst[1] = wkc;
    pp.src[2] = Wv;   pp.dst[2] = wvt;
    pp.src[3] = Wo;   pp.dst[3] = wot;
    pp.src[4] = f1W1; pp.dst[4] = f1w1t;
    pp.src[5] = f1W2; pp.dst[5] = f1w2t;
    pp.src[6] = f2W1; pp.dst[6] = f2w1t;
    pp.src[7] = f2W2; pp.dst[7] = f2w2t;
    // 1. weight prep + LN0 + argmax
    prep_ln0_k<<<5120 + NQ, 256, 0, stream>>>(pp, dec_output, mem_attn, g0, be0,
                                              x_f, x_b, smp);
    // 2. group queries by selected memory
    group_build_k<<<1, 1024, 0, stream>>>(smp, qcnt, qsta, qlst);
    // 3. QH = X @ Wq + bq  (bf16 out only)
    mfma_gemm<false, true, false, false, true><<<dim3(8, 16, 1), 256, 0, stream>>>(
        (const unsigned short*)x_b, wqt, nullptr, qh_b, bq, nullptr,
        DIM, DIM, DIM, DIM, 0, 0, 0, 0);
    // 4. U_h = QH_h @ Wk_h^T (batched heads, K=64)
    mfma_gemm<false, false, false, false, true><<<dim3(8, 16, NH), 256, 0, stream>>>(
        qh_b, wkc, nullptr, u_b, nullptr, nullptr,
        DHD, DIM, DIM, NH * DIM, DHD, DHD, DIM, 0);
    // 5. grouped key-split scores + partial softmax
    attn_scores_k<<<dim3(NMEM, 2), 256, 0, stream>>>(u_b, enc_mem, mask_mem,
                                                     qcnt, qsta, qlst, p_hlf, msc);
    // 6. grouped online-merge + PV -> a (bf16)
    attn_pv_k<<<dim3(NMEM, 4), 256, 0, stream>>>(p_hlf, msc, temb_mem,
                                                 qcnt, qsta, qlst, (unsigned*)a_b);
    // 7. CTX_h = A_h @ Wv_h + bv_h
    mfma_gemm<false, true, false, false, true><<<dim3(1, 16, NH), 256, 0, stream>>>(
        a_b, wvt, nullptr, qh_b, bv, nullptr,
        DIM, NH * DIM, DIM, DIM, DIM, DHD * DIM, DHD, DHD);
    // 8. ST0 = X + CTX @ Wo + bo
    mfma_gemm<false, true, true, true, true><<<dim3(8, 16, 1), 256, 0, stream>>>(
        qh_b, wot, st0_f, st0_b, bo, x_f, DIM, DIM, DIM, DIM, 0, 0, 0, 0);
    // 9. H1 = relu(ST0 @ f1W1 + f1b1)
    mfma_gemm<true, true, false, false, true><<<dim3(32, 16, 1), 256, 0, stream>>>(
        st0_b, f1w1t, nullptr, h1_b, f1b1, nullptr, DIM, DIM, DIM, DFF, 0, 0, 0, 0);
    // 10. T1 parts = H1 @ f1W2 (split-K=2; bias/res merged in LN1)
    mfma_gemm<false, false, false, true, false><<<dim3(8, 16, 2), 256, 0, stream>>>(
        h1_b, f1w2t, t1p_f, nullptr, nullptr, nullptr,
        1024, DFF, DFF, DIM, 1024, 1024, NQ * DIM, 0);
    // 11. DEC = X + mask * LN1(p0 + p1 + ST0 + f1b2)
    ln1_mask_add_k<<<NQ, 256, 0, stream>>>(t1p_f, st0_f, f1b2, g1, be1, smp,
                                           x_f, dec_f, dec_b);
    // 12. H2 = relu(DEC @ f2W1 + f2b1)
    mfma_gemm<true, true, false, false, true><<<dim3(32, 16, 1), 256, 0, stream>>>(
        (const unsigned short*)dec_b, f2w1t, nullptr, h2_b, f2b1, nullptr,
        DIM, DIM, DIM, DFF, 0, 0, 0, 0);
    // 13. OUT = DEC + H2 @ f2W2 + f2b2
    mfma_gemm<false, true, true, true, false><<<dim3(8, 16, 1), 256, 0, stream>>>(
        h2_b, f2w2t, out, nullptr, f2b2, dec_f, DFF, DFF, DFF, DIM, 0, 0, 0, 0);

    (void)in_sizes; (void)n_in; (void)out_size; (void)ws_size;
}

// Round 10
// 149.854 us; speedup vs baseline: 1.1816x; 1.1816x over previous
//
#include <hip/hip_runtime.h>
#include <math.h>

// Problem constants (fixed by the reference)
#define NQ   1024      // B*LT
#define DIM  512
#define NH   8
#define DHD  64
#define DFF  2048
#define LM   64        // LMEM

typedef __bf16 bf16x8 __attribute__((ext_vector_type(8)));
typedef float  f32x4  __attribute__((ext_vector_type(4)));

__device__ __forceinline__ unsigned short f2bf(float f) {
    unsigned u = __builtin_bit_cast(unsigned, f);
    return (unsigned short)((u + 0x7fffu + ((u >> 16) & 1u)) >> 16);
}
__device__ __forceinline__ float bflo(unsigned p) {
    return __builtin_bit_cast(float, p << 16);
}
__device__ __forceinline__ float bfhi(unsigned p) {
    return __builtin_bit_cast(float, p & 0xffff0000u);
}

__device__ __forceinline__ void gload16(const void* g, void* l) {
    __builtin_amdgcn_global_load_lds(
        (const __attribute__((address_space(1))) unsigned*)g,
        (__attribute__((address_space(3))) unsigned*)l, 16, 0, 0);
}

// ---------------------------------------------------------------- helpers
__device__ __forceinline__ float blk_sum(float v, volatile float* red) {
#pragma unroll
    for (int o = 32; o; o >>= 1) v += __shfl_down(v, o);
    __syncthreads();
    if ((threadIdx.x & 63) == 0) red[threadIdx.x >> 6] = v;
    __syncthreads();
    return red[0] + red[1] + red[2] + red[3];
}

// ------------------------------------------------- K1: weight-prep + LN0 + argmax
struct PrepPtrs {
    const float* src[8];
    unsigned short* dst[8];
};
// blocks [0,5120): weight prep; blocks [5120,6144): LN0+argmax for n = bid-5120
__global__ __launch_bounds__(256) void prep_ln0_k(
    PrepPtrs p,
    const float* __restrict__ dec_out, const float* __restrict__ attn_out,
    const float* __restrict__ g, const float* __restrict__ be,
    float* __restrict__ x, unsigned* __restrict__ xb, int* __restrict__ samples)
{
    __shared__ float tile[32][33];
    __shared__ float red[4];
    __shared__ float rv[4]; __shared__ int ri[4];
    const int bid = blockIdx.x;

    if (bid < 5120) {
        int m, lt;
        if (bid < 1024) { m = bid >> 8; lt = bid & 255; }
        else { m = 4 + ((bid - 1024) >> 10); lt = (bid - 1024) & 1023; }
        const int RS = (m < 4) ? 512 : ((m == 5 || m == 7) ? 2048 : 512);
        const int CS = (m < 4) ? 512 : ((m == 5 || m == 7) ? 512 : 2048);
        const int TC = CS >> 5;
        const int tr = lt / TC, tc = lt % TC;
        const float* s = p.src[m];
        unsigned short* d = p.dst[m];
        const int tx = threadIdx.x & 31, ty = threadIdx.x >> 5;
        if (m == 1) {
#pragma unroll
            for (int i = 0; i < 32; i += 8) {
                size_t idx = (size_t)(tr * 32 + ty + i) * CS + tc * 32 + tx;
                d[idx] = f2bf(s[idx]);
            }
        } else {
#pragma unroll
            for (int i = 0; i < 32; i += 8)
                tile[ty + i][tx] = s[(size_t)(tr * 32 + ty + i) * CS + tc * 32 + tx];
            __syncthreads();
#pragma unroll
            for (int i = 0; i < 32; i += 8)
                d[(size_t)(tc * 32 + ty + i) * RS + tr * 32 + tx] = f2bf(tile[tx][ty + i]);
        }
        return;
    }

    const int n = bid - 5120, t = threadIdx.x;
    float2 v = ((const float2*)(dec_out + (size_t)n * DIM))[t];
    float mu  = blk_sum(v.x + v.y, red) * (1.f / DIM);
    float dx = v.x - mu, dy = v.y - mu;
    float var = blk_sum(dx * dx + dy * dy, red) * (1.f / DIM);
    float rs = rsqrtf(var + 1e-5f);
    float2 gg = ((const float2*)g)[t], bb = ((const float2*)be)[t];
    float ox = dx * rs * gg.x + bb.x, oy = dy * rs * gg.y + bb.y;
    ((float2*)(x + (size_t)n * DIM))[t] = make_float2(ox, oy);
    xb[(size_t)n * 256 + t] = (unsigned)f2bf(ox) | ((unsigned)f2bf(oy) << 16);

    const float* ar = attn_out + (size_t)n * 1025;
    float bv = -INFINITY; int bi = 0x7fffffff;
    for (int i = t; i < 1025; i += 256) {
        float val = ar[i];
        if (val > bv || (val == bv && i < bi)) { bv = val; bi = i; }
    }
#pragma unroll
    for (int o = 32; o; o >>= 1) {
        float ov = __shfl_down(bv, o); int oi = __shfl_down(bi, o);
        if (ov > bv || (ov == bv && oi < bi)) { bv = ov; bi = oi; }
    }
    if ((t & 63) == 0) { rv[t >> 6] = bv; ri[t >> 6] = bi; }
    __syncthreads();
    if (t == 0) {
#pragma unroll
        for (int w = 1; w < 4; ++w)
            if (rv[w] > bv || (rv[w] == bv && ri[w] < bi)) { bv = rv[w]; bi = ri[w]; }
        samples[n] = bi - 1;
    }
}

// ------------------------------------------------- bf16 MFMA GEMM, 64x64 tile
// XCD-aware tile swizzle: requires gridDim.x*gridDim.y % 8 == 0.
template<bool RELU, bool BIAS, bool RES, bool WF32, bool WBF>
__global__ __launch_bounds__(256) void mfma_gemm(
    const unsigned short* __restrict__ A, const unsigned short* __restrict__ Bt,
    float* __restrict__ Cf, unsigned short* __restrict__ Cb,
    const float* __restrict__ bias, const float* __restrict__ res,
    int K, int lda, int ldb, int ldc,
    int sA, int sB, int sC, int sBias)
{
    __shared__ unsigned short Ab[2][64 * 64];
    __shared__ unsigned short Bb[2][64 * 64];
    const int t = threadIdx.x, lane = t & 63, wid = t >> 6;
    const int nx = gridDim.x;
    const int fid = blockIdx.y * nx + blockIdx.x;
    const int cpx = (nx * gridDim.y) >> 3;
    const int f2 = (fid & 7) * cpx + (fid >> 3);
    const int bn = (f2 % nx) * 64, bm = (f2 / nx) * 64, bz = blockIdx.z;
    const unsigned short* Abase = A + (size_t)bz * sA + (size_t)bm * lda;
    const unsigned short* Bbase = Bt + (size_t)bz * sB + (size_t)bn * ldb;

    const int r0 = wid * 16 + (lane >> 3);
    const int cbs = lane & 7;

#define STAGE_T(buf, base, ld, kt)                                              \
    {                                                                           \
        int r_ = r0;                                                            \
        gload16(base + (size_t)r_ * ld + (kt) * 64 + ((cbs ^ (r_ & 7)) << 3),   \
                &buf[(wid * 2 + 0) * 512]);                                     \
        r_ = r0 + 8;                                                            \
        gload16(base + (size_t)r_ * ld + (kt) * 64 + ((cbs ^ (r_ & 7)) << 3),   \
                &buf[(wid * 2 + 1) * 512]);                                     \
    }

    const int lr = lane & 15, lg = lane >> 4;
    const int wr = (wid >> 1) * 32, wc = (wid & 1) * 32;
    const int mA0 = wr + lr, mA1 = wr + 16 + lr;
    const int nB0 = wc + lr, nB1 = wc + 16 + lr;
    f32x4 acc[2][2] = {};

#define COMPUTE(b)                                                              \
    _Pragma("unroll")                                                           \
    for (int kk = 0; kk < 2; ++kk) {                                            \
        const int kb = kk * 4 + lg;                                             \
        bf16x8 a0 = *(const bf16x8*)&Ab[b][mA0 * 64 + ((kb ^ (mA0 & 7)) << 3)]; \
        bf16x8 a1 = *(const bf16x8*)&Ab[b][mA1 * 64 + ((kb ^ (mA1 & 7)) << 3)]; \
        bf16x8 b0 = *(const bf16x8*)&Bb[b][nB0 * 64 + ((kb ^ (nB0 & 7)) << 3)]; \
        bf16x8 b1 = *(const bf16x8*)&Bb[b][nB1 * 64 + ((kb ^ (nB1 & 7)) << 3)]; \
        acc[0][0] = __builtin_amdgcn_mfma_f32_16x16x32_bf16(a0, b0, acc[0][0], 0, 0, 0); \
        acc[0][1] = __builtin_amdgcn_mfma_f32_16x16x32_bf16(a0, b1, acc[0][1], 0, 0, 0); \
        acc[1][0] = __builtin_amdgcn_mfma_f32_16x16x32_bf16(a1, b0, acc[1][0], 0, 0, 0); \
        acc[1][1] = __builtin_amdgcn_mfma_f32_16x16x32_bf16(a1, b1, acc[1][1], 0, 0, 0); \
    }

    STAGE_T(Ab[0], Abase, lda, 0);
    STAGE_T(Bb[0], Bbase, ldb, 0);
    __syncthreads();
    const int NT = K >> 6;
    int cur = 0;
    for (int kt = 0; kt < NT; ++kt) {
        if (kt + 1 < NT) {
            STAGE_T(Ab[cur ^ 1], Abase, lda, kt + 1);
            STAGE_T(Bb[cur ^ 1], Bbase, ldb, kt + 1);
        }
        if (cur == 0) { COMPUTE(0); } else { COMPUTE(1); }
        __syncthreads();
        cur ^= 1;
    }

#pragma unroll
    for (int fm = 0; fm < 2; ++fm)
#pragma unroll
    for (int fn = 0; fn < 2; ++fn) {
        const int col = bn + wc + fn * 16 + lr;
        float bia = BIAS ? bias[bz * sBias + col] : 0.f;
#pragma unroll
        for (int r = 0; r < 4; ++r) {
            const int row = bm + wr + fm * 16 + lg * 4 + r;
            const size_t ci = (size_t)bz * sC + (size_t)row * ldc + col;
            float v = acc[fm][fn][r] + bia;
            if (RES) v += res[(size_t)row * ldc + col];
            if (RELU) v = fmaxf(v, 0.f);
            if (WF32) Cf[ci] = v;
            if (WBF)  Cb[ci] = f2bf(v);
        }
    }
#undef STAGE_T
#undef COMPUTE
}

// ------------------------------------------------- K4: fused attention, wave-specialized
// Block n (512 threads): waves 0-3 scores+softmax (enc stream), waves 4-7 PV
// (V stream, prefetched concurrently with scores). Both gathers in flight at once.
__global__ __launch_bounds__(512) void attn_fused_k(
    const unsigned short* __restrict__ u_bf, const float* __restrict__ enc,
    const float* __restrict__ vemb, const int* __restrict__ maskmem,
    const int* __restrict__ samples, unsigned* __restrict__ a_bf)
{
    __shared__ float S_lds[8 * 68];
    __shared__ uint4 P_lds[64];       // [key][8 heads] bf16
    __shared__ int Msk_lds[64];
    const int n = blockIdx.x, t = threadIdx.x;
    const int lane = t & 63, w = t >> 6;
    int s = samples[n]; if (s < 0) s = 0;

    float2 pfv[8];
    const float2* vb = (const float2*)(vemb + (size_t)s * (LM * DIM)) + (t - 256);

    if (w >= 4) {
        // PV waves: thread owns dim-pair (t-256) in [0,256); prefetch keys 0..7
#pragma unroll
        for (int i = 0; i < 8; ++i) pfv[i] = vb[(size_t)i * 256];
        if (w == 4) Msk_lds[lane] = maskmem[(size_t)s * LM + lane];
    } else {
        // scores waves: wave w -> keys [w*16, w*16+16), full K=512 in 16 steps
        const float4* kb = (const float4*)(enc + (size_t)s * (LM * DIM));
        const int key = w * 16 + (lane & 15);
        const int lg = lane >> 4;
        const int h = lane & 15;
        const int base = key * 128 + lg * 2;  // float4 units
        float4 pf[4][2];
#pragma unroll
        for (int ss = 0; ss < 4; ++ss) {
            pf[ss][0] = kb[base + ss * 8];
            pf[ss][1] = kb[base + ss * 8 + 1];
        }
        const unsigned short* ub = u_bf + (size_t)n * 4096 + (size_t)(h & 7) * 512;
        f32x4 acc = {};
#pragma unroll
        for (int step = 0; step < 16; ++step) {
            float4 a0 = pf[step & 3][0], a1 = pf[step & 3][1];
            if (step + 4 < 16) {
                pf[step & 3][0] = kb[base + (step + 4) * 8];
                pf[step & 3][1] = kb[base + (step + 4) * 8 + 1];
            }
            bf16x8 af;
            af[0] = (__bf16)a0.x; af[1] = (__bf16)a0.y;
            af[2] = (__bf16)a0.z; af[3] = (__bf16)a0.w;
            af[4] = (__bf16)a1.x; af[5] = (__bf16)a1.y;
            af[6] = (__bf16)a1.z; af[7] = (__bf16)a1.w;
            bf16x8 bfr = *(const bf16x8*)&ub[(step * 4 + lg) * 8];
            acc = __builtin_amdgcn_mfma_f32_16x16x32_bf16(af, bfr, acc, 0, 0, 0);
        }
        if (h < 8) {
#pragma unroll
            for (int r = 0; r < 4; ++r)
                S_lds[h * 68 + w * 16 + lg * 4 + r] = acc[r];
        }
    }
    __syncthreads();   // S_lds + Msk ready

    if (w < 4) {
        // softmax over full 64 keys: wave w handles heads w and w+4
#pragma unroll
        for (int hh = 0; hh < 2; ++hh) {
            const int h2 = w + hh * 4;
            float sc = S_lds[h2 * 68 + lane] * 0.125f;
            sc = (Msk_lds[lane] != 0) ? sc : -1e9f;
            float m = sc;
#pragma unroll
            for (int o = 32; o; o >>= 1) m = fmaxf(m, __shfl_xor(m, o));
            float e = __expf(sc - m);
            float su = e;
#pragma unroll
            for (int o = 32; o; o >>= 1) su += __shfl_xor(su, o);
            ((unsigned short*)P_lds)[lane * 8 + h2] = f2bf(e / su);
        }
    }
    __syncthreads();   // P ready

    if (w >= 4) {
        float2 acc8[8];
#pragma unroll
        for (int hh = 0; hh < 8; ++hh) acc8[hh] = make_float2(0.f, 0.f);
#pragma unroll 8
        for (int k = 0; k < 64; ++k) {
            float2 v = pfv[k & 7];
            if (k + 8 < 64) pfv[k & 7] = vb[(size_t)(k + 8) * 256];
            uint4 pr = P_lds[k];
            float p0 = bflo(pr.x), p1 = bfhi(pr.x);
            float p2 = bflo(pr.y), p3 = bfhi(pr.y);
            float p4 = bflo(pr.z), p5 = bfhi(pr.z);
            float p6 = bflo(pr.w), p7 = bfhi(pr.w);
            acc8[0].x = fmaf(p0, v.x, acc8[0].x); acc8[0].y = fmaf(p0, v.y, acc8[0].y);
            acc8[1].x = fmaf(p1, v.x, acc8[1].x); acc8[1].y = fmaf(p1, v.y, acc8[1].y);
            acc8[2].x = fmaf(p2, v.x, acc8[2].x); acc8[2].y = fmaf(p2, v.y, acc8[2].y);
            acc8[3].x = fmaf(p3, v.x, acc8[3].x); acc8[3].y = fmaf(p3, v.y, acc8[3].y);
            acc8[4].x = fmaf(p4, v.x, acc8[4].x); acc8[4].y = fmaf(p4, v.y, acc8[4].y);
            acc8[5].x = fmaf(p5, v.x, acc8[5].x); acc8[5].y = fmaf(p5, v.y, acc8[5].y);
            acc8[6].x = fmaf(p6, v.x, acc8[6].x); acc8[6].y = fmaf(p6, v.y, acc8[6].y);
            acc8[7].x = fmaf(p7, v.x, acc8[7].x); acc8[7].y = fmaf(p7, v.y, acc8[7].y);
        }
        unsigned* an = a_bf + (size_t)n * 2048 + (t - 256);
#pragma unroll
        for (int hh = 0; hh < 8; ++hh)
            an[hh * 256] = (unsigned)f2bf(acc8[hh].x) | ((unsigned)f2bf(acc8[hh].y) << 16);
    }
}

// ------------------------------------------------- K9: combine T1 parts + LN + mask + x
__global__ __launch_bounds__(256) void ln1_mask_add_k(
    const float* __restrict__ t1p, const float* __restrict__ st0,
    const float* __restrict__ b2, const float* __restrict__ g,
    const float* __restrict__ be, const int* __restrict__ samples,
    const float* __restrict__ x, float* __restrict__ dec, unsigned* __restrict__ decb)
{
    __shared__ float red[4];
    const int n = blockIdx.x, t = threadIdx.x;
    const size_t off = (size_t)n * DIM + t * 2;
    float2 p0 = *(const float2*)&t1p[off];
    float2 p1 = *(const float2*)&t1p[(size_t)NQ * DIM + off];
    float2 s0 = *(const float2*)&st0[off];
    float2 b2v = ((const float2*)b2)[t];
    float2 v = make_float2(p0.x + p1.x + s0.x + b2v.x, p0.y + p1.y + s0.y + b2v.y);
    float mu  = blk_sum(v.x + v.y, red) * (1.f / DIM);
    float dx = v.x - mu, dy = v.y - mu;
    float var = blk_sum(dx * dx + dy * dy, red) * (1.f / DIM);
    float rs = rsqrtf(var + 1e-5f);
    float2 gg = ((const float2*)g)[t], bb = ((const float2*)be)[t];
    float sx = dx * rs * gg.x + bb.x, sy = dy * rs * gg.y + bb.y;
    if (samples[n] < 0) { sx = 0.f; sy = 0.f; }
    float2 xx = *(const float2*)&x[off];
    float ox = xx.x + sx, oy = xx.y + sy;
    *(float2*)&dec[off] = make_float2(ox, oy);
    decb[(size_t)n * 256 + t] = (unsigned)f2bf(ox) | ((unsigned)f2bf(oy) << 16);
}

// ---------------------------------------------------------------- launcher
extern "C" void kernel_launch(void* const* d_in, const int* in_sizes, int n_in,
                              void* d_out, int out_size, void* d_ws, size_t ws_size,
                              hipStream_t stream)
{
    const float* dec_output = (const float*)d_in[0];
    const float* mem_attn   = (const float*)d_in[1];
    const float* enc_mem    = (const float*)d_in[2];
    const float* temb_mem   = (const float*)d_in[3];
    const int*   mask_mem   = (const int*)d_in[4];
    const float* g0  = (const float*)d_in[6];
    const float* be0 = (const float*)d_in[7];
    const float* g1  = (const float*)d_in[8];
    const float* be1 = (const float*)d_in[9];
    const float* Wq  = (const float*)d_in[10];
    const float* bq  = (const float*)d_in[11];
    const float* Wk  = (const float*)d_in[12];
    const float* Wv  = (const float*)d_in[14];
    const float* bv  = (const float*)d_in[15];
    const float* Wo  = (const float*)d_in[16];
    const float* bo  = (const float*)d_in[17];
    const float* f1W1 = (const float*)d_in[18];
    const float* f1b1 = (const float*)d_in[19];
    const float* f1W2 = (const float*)d_in[20];
    const float* f1b2 = (const float*)d_in[21];
    const float* f2W1 = (const float*)d_in[22];
    const float* f2b1 = (const float*)d_in[23];
    const float* f2W2 = (const float*)d_in[24];
    const float* f2b2 = (const float*)d_in[25];
    float* out = (float*)d_out;

    float* ws = (float*)d_ws;
    // persistent (offsets in floats)
    float*          x_f   = ws + 0;                          // 524288
    unsigned*       x_b   = (unsigned*)(ws + 524288);        // 262144
    unsigned short* qh_b  = (unsigned short*)(ws + 786432);  // 262144
    unsigned short* u_b   = (unsigned short*)(ws + 1048576); // 2097152
    unsigned short* a_b   = (unsigned short*)(ws + 3145728); // 2097152
    unsigned short* wqt   = (unsigned short*)(ws + 7340032); // 131072 each
    unsigned short* wkc   = (unsigned short*)(ws + 7471104);
    unsigned short* wvt   = (unsigned short*)(ws + 7602176);
    unsigned short* wot   = (unsigned short*)(ws + 7733248);
    unsigned short* f1w1t = (unsigned short*)(ws + 7864320); // 524288 each
    unsigned short* f1w2t = (unsigned short*)(ws + 8388608);
    unsigned short* f2w1t = (unsigned short*)(ws + 8912896);
    unsigned short* f2w2t = (unsigned short*)(ws + 9437184);
    int*            smp   = (int*)(ws + 9961472);            // 1024
    float*          t1p_f = ws + 9962496;                    // 1048576 (2 parts)
    // aliases inside u_b region (u dead after attn_fused):
    float*          st0_f = (float*)u_b + 0;                 // 524288
    unsigned short* st0_b = (unsigned short*)((float*)u_b + 524288); // 131072
    float*          dec_f = (float*)u_b + 655360;            // 524288
    unsigned*       dec_b = (unsigned*)((float*)u_b + 1179648); // 131072
    // aliases inside a_b region (a dead after CTX GEMM):
    unsigned short* h1_b  = a_b;                             // 1024x2048 bf16
    unsigned short* h2_b  = (unsigned short*)((float*)a_b + 1048576);

    PrepPtrs pp;
    pp.src[0] = Wq;   pp.dst[0] = wqt;
    pp.src[1] = Wk;   pp.dst[1] = wkc;
    pp.src[2] = Wv;   pp.dst[2] = wvt;
    pp.src[3] = Wo;   pp.dst[3] = wot;
    pp.src[4] = f1W1; pp.dst[4] = f1w1t;
    pp.src[5] = f1W2; pp.dst[5] = f1w2t;
    pp.src[6] = f2W1; pp.dst[6] = f2w1t;
    pp.src[7] = f2W2; pp.dst[7] = f2w2t;
    // 1. weight prep + LN0 + argmax
    prep_ln0_k<<<5120 + NQ, 256, 0, stream>>>(pp, dec_output, mem_attn, g0, be0,
                                              x_f, x_b, smp);
    // 2. QH = X @ Wq + bq  (bf16 out only)
    mfma_gemm<false, true, false, false, true><<<dim3(8, 16, 1), 256, 0, stream>>>(
        (const unsigned short*)x_b, wqt, nullptr, qh_b, bq, nullptr,
        DIM, DIM, DIM, DIM, 0, 0, 0, 0);
    // 3. U_h = QH_h @ Wk_h^T (batched heads, K=64)
    mfma_gemm<false, false, false, false, true><<<dim3(8, 16, NH), 256, 0, stream>>>(
        qh_b, wkc, nullptr, u_b, nullptr, nullptr,
        DHD, DIM, DIM, NH * DIM, DHD, DHD, DIM, 0);
    // 4. fused attention (scores + softmax + PV, wave-specialized)
    attn_fused_k<<<NQ, 512, 0, stream>>>(u_b, enc_mem, temb_mem, mask_mem, smp,
                                         (unsigned*)a_b);
    // 5. CTX_h = A_h @ Wv_h + bv_h
    mfma_gemm<false, true, false, false, true><<<dim3(1, 16, NH), 256, 0, stream>>>(
        a_b, wvt, nullptr, qh_b, bv, nullptr,
        DIM, NH * DIM, DIM, DIM, DIM, DHD * DIM, DHD, DHD);
    // 6. ST0 = X + CTX @ Wo + bo
    mfma_gemm<false, true, true, true, true><<<dim3(8, 16, 1), 256, 0, stream>>>(
        qh_b, wot, st0_f, st0_b, bo, x_f, DIM, DIM, DIM, DIM, 0, 0, 0, 0);
    // 7. H1 = relu(ST0 @ f1W1 + f1b1)
    mfma_gemm<true, true, false, false, true><<<dim3(32, 16, 1), 256, 0, stream>>>(
        st0_b, f1w1t, nullptr, h1_b, f1b1, nullptr, DIM, DIM, DIM, DFF, 0, 0, 0, 0);
    // 8. T1 parts = H1 @ f1W2 (split-K=2; bias/res merged in LN1)
    mfma_gemm<false, false, false, true, false><<<dim3(8, 16, 2), 256, 0, stream>>>(
        h1_b, f1w2t, t1p_f, nullptr, nullptr, nullptr,
        1024, DFF, DFF, DIM, 1024, 1024, NQ * DIM, 0);
    // 9. DEC = X + mask * LN1(p0 + p1 + ST0 + f1b2)
    ln1_mask_add_k<<<NQ, 256, 0, stream>>>(t1p_f, st0_f, f1b2, g1, be1, smp,
                                           x_f, dec_f, dec_b);
    // 10. H2 = relu(DEC @ f2W1 + f2b1)
    mfma_gemm<true, true, false, false, true><<<dim3(32, 16, 1), 256, 0, stream>>>(
        (const unsigned short*)dec_b, f2w1t, nullptr, h2_b, f2b1, nullptr,
        DIM, DIM, DIM, DFF, 0, 0, 0, 0);
    // 11. OUT = DEC + H2 @ f2W2 + f2b2
    mfma_gemm<false, true, true, true, false><<<dim3(8, 16, 1), 256, 0, stream>>>(
        h2_b, f2w2t, out, nullptr, f2b2, dec_f, DFF, DFF, DFF, DIM, 0, 0, 0, 0);

    (void)in_sizes; (void)n_in; (void)out_size; (void)ws_size;
}